// Round 15
// baseline (77.274 us; speedup 1.0000x reference)
//
#include <hip/hip_runtime.h>
#include <cmath>

// Problem constants (fixed by the reference's init kwargs):
//   POS_FREQS=31, W_MIN=0.1, W_MAX=1.0, PATCH=16 -> grid H=64 (row 63 padded), W=32
//   batch_triangles: [64,128,3,2] f32, lengths: [64] i32
//   outputs: mag [64,1,64,32] f32 then phase [64,1,64,32] f32, concatenated flat.
#define BB     64
#define MAXN   128
#define HH     64
#define WW     32
#define NFREQ  (HH*WW)      // 2048
#define BLK    256
#define NWAVE  4            // waves per block; each wave covers 64 points
#define PGRPS  (NFREQ/64)   // 32 point-groups of 64 points per batch elem

// pos_w[k] = float32(0.1 * (10^(1/30))^k) — bit-exactness validated in R10/R11.
__device__ __constant__ float c_posw[31] = {
    0.10000000000f, 0.10797751623f, 0.11659144012f, 0.12589254118f,
    0.13593563909f, 0.14677992676f, 0.15848931925f, 0.17113283042f,
    0.18478497970f, 0.19952623150f, 0.21544346900f, 0.23263050672f,
    0.25118864315f, 0.27122725793f, 0.29286445646f, 0.31622776602f,
    0.34145488738f, 0.36869450645f, 0.39810717055f, 0.42986623483f,
    0.46415888336f, 0.50118723363f, 0.54116952655f, 0.58434141336f,
    0.63095734448f, 0.68129206906f, 0.73564225446f, 0.79432823472f,
    0.85769589859f, 0.92611872813f, 1.00000000000f
};

// float32 constants exactly as the reference builds them:
#define PI_F      3.14159274101257324f   // np.float32(np.pi)
#define TWOPI_F   6.28318548202514648f   // 2*pi_f
#define FOURPI2_F ((4.0f * PI_F) * PI_F) // np.float32(4)*pi*pi

// sin(2*pi*x), cos(2*pi*x) via hardware v_sin_f32/v_cos_f32 (input in
// REVOLUTIONS, reduced to [0,1) with v_fract_f32 first).
__device__ __forceinline__ void sincos_2pi(float x, float* s, float* c) {
    float r = __builtin_amdgcn_fractf(x);
    *s = __builtin_amdgcn_sinf(r);
    *c = __builtin_amdgcn_cosf(r);
}

// Per-triangle precomputation shared by both paths: mask quantities
// (exact mul/mul/add, no FMA contraction), 3 sincos, staged constants.
struct Pre {
    float U_, V_, S;
    float z2;              // 2*area (exact)
    float zk;              // 2*area/(4pi^2) (pre-scaled for the fast path)
    float sq, cq, sr, cr, ss, cs;
    bool  uz, vz, sz, sp;
};

__device__ __forceinline__ Pre pre_eval(float U, float V, float4 A4, float4 B4) {
    Pre e;
    e.U_ = __fadd_rn(__fmul_rn(U, A4.z), __fmul_rn(V, A4.w));
    e.V_ = __fadd_rn(__fmul_rn(U, B4.x), __fmul_rn(V, B4.y));
    e.S  = __fadd_rn(e.U_, e.V_);
    e.uz = (e.U_ == 0.0f);
    e.vz = (e.V_ == 0.0f);
    e.sz = (e.S  == 0.0f);
    e.sp = e.uz || e.vz || e.sz;
    // Exponential args (not mask-relevant; FMA fine). t_r/t_s exact when
    // U_/V_ are exactly 0 (adding exact zero), as the special cases need.
    const float tq = U * A4.x + V * A4.y;
    const float tr = tq + e.U_;
    const float ts = tr + e.V_;
    sincos_2pi(tq, &e.sq, &e.cq);
    sincos_2pi(tr, &e.sr, &e.cr);
    sincos_2pi(ts, &e.ss, &e.cs);
    e.z2 = B4.z;
    e.zk = B4.w;
    return e;
}

// SLOW path: the round-5-validated branchless 4-way coefficient code
// (text preserved; valid for ALL cases). area = 0.5f*(2*area) exact.
__device__ __forceinline__ void eval_slow(const Pre& e, float& accR, float& accI) {
    const float area = 0.5f * e.z2;
    const bool zero = e.uz && e.vz;
    const bool diag = e.sz && !zero;
    const bool u_m  = e.uz && !zero;
    const bool v_m  = e.vz && !zero;
    const bool nrm  = !(e.uz || e.vz || e.sz);

    const float twU = TWOPI_F * e.U_;
    const float twV = TWOPI_F * e.V_;

    const float Ac = nrm ? -e.U_ : (u_m ? 1.0f : 0.0f);
    const float Bc = nrm ?  e.S  : ((diag || v_m) ? 1.0f : 0.0f);
    const float Cc = nrm ? -e.V_ : -1.0f;
    const float Dc = v_m  ? twU : 0.0f;
    const float Ec = diag ? twU : (u_m ? twV : 0.0f);

    const float d1  = u_m ? e.V_ : e.U_;
    const float den = nrm ? (e.U_ * e.V_) * e.S : d1 * d1;
    const float p1  = __builtin_amdgcn_rcpf(FOURPI2_F * den);
    const float sgn = (diag || u_m) ? -2.0f : 2.0f;
    const float k   = zero ? 0.0f : sgn * area * p1;

    const float re =  Ac * e.cs + Bc * e.cr + Cc * e.cq + Dc * e.sr + Ec * e.sq;
    const float im = -(Ac * e.ss + Bc * e.sr + Cc * e.sq) + Dc * e.cr + Ec * e.cq;

    accR = fmaf(k, re, accR) + (zero ? area : 0.0f);
    accI = fmaf(k, im, accI);
}

// FAST path: pure normal-case algebra; k = (2*area/4pi^2) * rcp(U_ V_ S).
__device__ __forceinline__ void eval_fast(const Pre& e, float& accR, float& accI) {
    const float p1 = __builtin_amdgcn_rcpf((e.U_ * e.V_) * e.S);
    const float k  = e.zk * p1;
    const float re = e.S * e.cr - e.U_ * e.cs - e.V_ * e.cq;
    const float im = e.U_ * e.ss - e.S * e.sr + e.V_ * e.sq;
    accR = fmaf(k, re, accR);
    accI = fmaf(k, im, accI);
}

// Fused kernel, R13 body. R14 single-variable change: 1-D grid with b-FAST
// block mapping (b = L & 63, pg = L >> 6) so any contiguous run of blocks
// spans all 64 batch elems — per-CU work ~= mean under ANY placement policy.
// Previously all 32 blocks of one b were dispatch-contiguous; with every
// block resident (2048 blocks = 8/CU) and cost ~ N_b, linear placement made
// the kernel run at max-CU time (~2x127-eval blocks/SIMD) not mean-CU time.
__global__ __launch_bounds__(BLK) void poly_cft_fused(
    const float* __restrict__ tris,    // [64,128,3,2]
    const int*   __restrict__ lengths, // [64]
    float*       __restrict__ out)     // [2*64*2048]
{
    __shared__ float4 sA[MAXN];           // xq, yq, e1x, e1y          (2 KB)
    __shared__ float4 sB[MAXN];           // e2x, e2y, 2a, 2a/4pi^2    (2 KB)
    __shared__ float2 s_red[NWAVE][64];   // reduction scratch         (2 KB)

    const int L    = blockIdx.x;           // 0..2047
    const int b    = L & 63;               // FAST-varying: mixes N_b per CU
    const int pg   = L >> 6;               // 0..31 point group
    const int lane = threadIdx.x & 63;
    const int wv   = threadIdx.x >> 6;     // 0..3 wave id
    const int p    = (pg << 6) | lane;     // 0..2047 freq point
    const int h    = p >> 5;
    const int w    = p & 31;

    const int N = lengths[b];

    // Stage all 128 triangles of this b once per block.
    if (threadIdx.x < MAXN) {
        const float2* tp = (const float2*)(tris + ((size_t)b * MAXN + threadIdx.x) * 6);
        const float2 v0 = tp[0], v1 = tp[1], v2 = tp[2];
        const float xq = v0.x, yq = v0.y, xr = v1.x, yr = v1.y, xs = v2.x, ys = v2.y;
        const float det  = xq * (yr - ys) + xr * (ys - yq) + xs * (yq - yr);
        const float area = fabsf(0.5f * det);
        const float a2   = 2.0f * area;
        sA[threadIdx.x] = make_float4(xq, yq, xr - xq, yr - yq);
        sB[threadIdx.x] = make_float4(xs - xr, ys - yr, a2, a2 * (1.0f / FOURPI2_F));
    }
    __syncthreads();

    // U = Wx[h], V = Wy[w] from the validated constant table.
    float U;
    if (h < 31)       U = -c_posw[30 - h];
    else if (h == 31) U = 0.0f;
    else if (h < 63)  U = c_posw[h - 32];
    else              U = 0.0f;   // padded row (masked before output)
    const float V = (w == 0) ? 0.0f : c_posw[w - 1];

    float accR = 0.0f, accI = 0.0f;

    // Quad loop: wave wv evaluates (n, n+4, n+8, n+12) together; per-wave
    // accumulation order (wv, wv+4, wv+8, ...) is preserved exactly.
    int n = wv;
    for (; n + 3 * NWAVE < N; n += 4 * NWAVE) {
        const Pre ea = pre_eval(U, V, sA[n],             sB[n]);
        const Pre eb = pre_eval(U, V, sA[n +     NWAVE], sB[n +     NWAVE]);
        const Pre ec = pre_eval(U, V, sA[n + 2 * NWAVE], sB[n + 2 * NWAVE]);
        const Pre ed = pre_eval(U, V, sA[n + 3 * NWAVE], sB[n + 3 * NWAVE]);

        if (__ballot(ea.sp || eb.sp || ec.sp || ed.sp)) {
            eval_slow(ea, accR, accI);
            eval_slow(eb, accR, accI);
            eval_slow(ec, accR, accI);
            eval_slow(ed, accR, accI);
        } else {
            eval_fast(ea, accR, accI);
            eval_fast(eb, accR, accI);
            eval_fast(ec, accR, accI);
            eval_fast(ed, accR, accI);
        }
    }

    // Pair remainder.
    for (; n + NWAVE < N; n += 2 * NWAVE) {
        const Pre ea = pre_eval(U, V, sA[n],         sB[n]);
        const Pre eb = pre_eval(U, V, sA[n + NWAVE], sB[n + NWAVE]);
        if (__ballot(ea.sp || eb.sp)) {
            eval_slow(ea, accR, accI);
            eval_slow(eb, accR, accI);
        } else {
            eval_fast(ea, accR, accI);
            eval_fast(eb, accR, accI);
        }
    }

    // Single remainder (at most one triangle per wave).
    for (; n < N; n += NWAVE) {
        const Pre ea = pre_eval(U, V, sA[n], sB[n]);
        if (__ballot(ea.sp)) {
            eval_slow(ea, accR, accI);
        } else {
            eval_fast(ea, accR, accI);
        }
    }

    s_red[wv][lane] = make_float2(accR, accI);
    __syncthreads();

    if (wv == 0) {
        float R = 0.0f, I = 0.0f;
#pragma unroll
        for (int k = 0; k < NWAVE; ++k) {
            const float2 v = s_red[k][lane];
            R += v.x;
            I += v.y;
        }
        // numpy's masked segment-sum adds exact +0.0 for invalid slots,
        // flipping -0.0 -> +0.0; reproduce (affects only zero signs).
        R += 0.0f;
        I += 0.0f;

        if (h == 63) { R = 0.0f; I = 0.0f; }   // pad row

        const float m2 = __fadd_rn(__fmul_rn(R, R), __fmul_rn(I, I));
        float mag, ph;
        if (m2 == 0.0f) {
            mag = 0.0f;
            ph  = atan2f(I, 1.0f);   // angle(0) = 0 semantics
        } else {
            mag = log1pf(sqrtf(m2));
            ph  = atan2f(I, R);
        }

        const int o = b * NFREQ + p;
        out[o]              = mag;   // mag block [64,1,64,32]
        out[BB * NFREQ + o] = ph;    // phase block follows
    }
}

extern "C" void kernel_launch(void* const* d_in, const int* in_sizes, int n_in,
                              void* d_out, int out_size, void* d_ws, size_t ws_size,
                              hipStream_t stream) {
    const float* tris    = (const float*)d_in[0]; // [64,128,3,2] f32
    const int*   lengths = (const int*)d_in[1];   // [64] i32
    float*       out     = (float*)d_out;         // [2*64*2048] f32

    poly_cft_fused<<<dim3(PGRPS * BB), dim3(BLK), 0, stream>>>(tris, lengths, out);
}

// Round 16
// 73.929 us; speedup vs baseline: 1.0452x; 1.0452x over previous
//
#include <hip/hip_runtime.h>
#include <cmath>

// Problem constants (fixed by the reference's init kwargs):
//   POS_FREQS=31, W_MIN=0.1, W_MAX=1.0, PATCH=16 -> grid H=64 (row 63 padded), W=32
//   batch_triangles: [64,128,3,2] f32, lengths: [64] i32
//   outputs: mag [64,1,64,32] f32 then phase [64,1,64,32] f32, concatenated flat.
//
// R15 = exact revert to the round-13 best (73.86 us). R14's b-fast block
// mapping regressed (+3.4 us): dispatch does NOT place contiguous blocks
// linearly per CU, so the balance theory bought nothing and lost the
// same-b L1/L2 staging locality. 2-D (pg, b) grid restored.
#define BB     64
#define MAXN   128
#define HH     64
#define WW     32
#define NFREQ  (HH*WW)      // 2048
#define BLK    256
#define NWAVE  4            // waves per block; each wave covers 64 points
#define PGRPS  (NFREQ/64)   // 32 point-groups of 64 points per batch elem

// pos_w[k] = float32(0.1 * (10^(1/30))^k) — bit-exactness validated in R10/R11.
__device__ __constant__ float c_posw[31] = {
    0.10000000000f, 0.10797751623f, 0.11659144012f, 0.12589254118f,
    0.13593563909f, 0.14677992676f, 0.15848931925f, 0.17113283042f,
    0.18478497970f, 0.19952623150f, 0.21544346900f, 0.23263050672f,
    0.25118864315f, 0.27122725793f, 0.29286445646f, 0.31622776602f,
    0.34145488738f, 0.36869450645f, 0.39810717055f, 0.42986623483f,
    0.46415888336f, 0.50118723363f, 0.54116952655f, 0.58434141336f,
    0.63095734448f, 0.68129206906f, 0.73564225446f, 0.79432823472f,
    0.85769589859f, 0.92611872813f, 1.00000000000f
};

// float32 constants exactly as the reference builds them:
#define PI_F      3.14159274101257324f   // np.float32(np.pi)
#define TWOPI_F   6.28318548202514648f   // 2*pi_f
#define FOURPI2_F ((4.0f * PI_F) * PI_F) // np.float32(4)*pi*pi

// sin(2*pi*x), cos(2*pi*x) via hardware v_sin_f32/v_cos_f32 (input in
// REVOLUTIONS, reduced to [0,1) with v_fract_f32 first).
__device__ __forceinline__ void sincos_2pi(float x, float* s, float* c) {
    float r = __builtin_amdgcn_fractf(x);
    *s = __builtin_amdgcn_sinf(r);
    *c = __builtin_amdgcn_cosf(r);
}

// Per-triangle precomputation shared by both paths: mask quantities
// (exact mul/mul/add, no FMA contraction), 3 sincos, staged constants.
struct Pre {
    float U_, V_, S;
    float z2;              // 2*area (exact)
    float zk;              // 2*area/(4pi^2) (pre-scaled for the fast path)
    float sq, cq, sr, cr, ss, cs;
    bool  uz, vz, sz, sp;
};

__device__ __forceinline__ Pre pre_eval(float U, float V, float4 A4, float4 B4) {
    Pre e;
    e.U_ = __fadd_rn(__fmul_rn(U, A4.z), __fmul_rn(V, A4.w));
    e.V_ = __fadd_rn(__fmul_rn(U, B4.x), __fmul_rn(V, B4.y));
    e.S  = __fadd_rn(e.U_, e.V_);
    e.uz = (e.U_ == 0.0f);
    e.vz = (e.V_ == 0.0f);
    e.sz = (e.S  == 0.0f);
    e.sp = e.uz || e.vz || e.sz;
    // Exponential args (not mask-relevant; FMA fine). t_r/t_s exact when
    // U_/V_ are exactly 0 (adding exact zero), as the special cases need.
    const float tq = U * A4.x + V * A4.y;
    const float tr = tq + e.U_;
    const float ts = tr + e.V_;
    sincos_2pi(tq, &e.sq, &e.cq);
    sincos_2pi(tr, &e.sr, &e.cr);
    sincos_2pi(ts, &e.ss, &e.cs);
    e.z2 = B4.z;
    e.zk = B4.w;
    return e;
}

// SLOW path: the round-5-validated branchless 4-way coefficient code
// (text preserved; valid for ALL cases). area = 0.5f*(2*area) exact.
__device__ __forceinline__ void eval_slow(const Pre& e, float& accR, float& accI) {
    const float area = 0.5f * e.z2;
    const bool zero = e.uz && e.vz;
    const bool diag = e.sz && !zero;
    const bool u_m  = e.uz && !zero;
    const bool v_m  = e.vz && !zero;
    const bool nrm  = !(e.uz || e.vz || e.sz);

    const float twU = TWOPI_F * e.U_;
    const float twV = TWOPI_F * e.V_;

    const float Ac = nrm ? -e.U_ : (u_m ? 1.0f : 0.0f);
    const float Bc = nrm ?  e.S  : ((diag || v_m) ? 1.0f : 0.0f);
    const float Cc = nrm ? -e.V_ : -1.0f;
    const float Dc = v_m  ? twU : 0.0f;
    const float Ec = diag ? twU : (u_m ? twV : 0.0f);

    const float d1  = u_m ? e.V_ : e.U_;
    const float den = nrm ? (e.U_ * e.V_) * e.S : d1 * d1;
    const float p1  = __builtin_amdgcn_rcpf(FOURPI2_F * den);
    const float sgn = (diag || u_m) ? -2.0f : 2.0f;
    const float k   = zero ? 0.0f : sgn * area * p1;

    const float re =  Ac * e.cs + Bc * e.cr + Cc * e.cq + Dc * e.sr + Ec * e.sq;
    const float im = -(Ac * e.ss + Bc * e.sr + Cc * e.sq) + Dc * e.cr + Ec * e.cq;

    accR = fmaf(k, re, accR) + (zero ? area : 0.0f);
    accI = fmaf(k, im, accI);
}

// FAST path: pure normal-case algebra; k = (2*area/4pi^2) * rcp(U_ V_ S).
__device__ __forceinline__ void eval_fast(const Pre& e, float& accR, float& accI) {
    const float p1 = __builtin_amdgcn_rcpf((e.U_ * e.V_) * e.S);
    const float k  = e.zk * p1;
    const float re = e.S * e.cr - e.U_ * e.cs - e.V_ * e.cq;
    const float im = e.U_ * e.ss - e.S * e.sr + e.V_ * e.sq;
    accR = fmaf(k, re, accR);
    accI = fmaf(k, im, accI);
}

// Fused kernel: 4 waves share 64 points; triangles staged once per block in
// LDS; waves split triangles stride-4 and process QUADS (n,n+4,n+8,n+12)
// per iteration with a single ballot — 12 sincos + 4 mask computations in
// one basic block for 4-wide ILP. LDS 4->1 reduction; direct output.
__global__ __launch_bounds__(BLK) void poly_cft_fused(
    const float* __restrict__ tris,    // [64,128,3,2]
    const int*   __restrict__ lengths, // [64]
    float*       __restrict__ out)     // [2*64*2048]
{
    __shared__ float4 sA[MAXN];           // xq, yq, e1x, e1y          (2 KB)
    __shared__ float4 sB[MAXN];           // e2x, e2y, 2a, 2a/4pi^2    (2 KB)
    __shared__ float2 s_red[NWAVE][64];   // reduction scratch         (2 KB)

    const int pg   = blockIdx.x;           // 0..31 point group
    const int b    = blockIdx.y;           // 0..63 batch elem
    const int lane = threadIdx.x & 63;
    const int wv   = threadIdx.x >> 6;     // 0..3 wave id
    const int p    = (pg << 6) | lane;     // 0..2047 freq point
    const int h    = p >> 5;
    const int w    = p & 31;

    const int N = lengths[b];

    // Stage all 128 triangles of this b once per block.
    if (threadIdx.x < MAXN) {
        const float2* tp = (const float2*)(tris + ((size_t)b * MAXN + threadIdx.x) * 6);
        const float2 v0 = tp[0], v1 = tp[1], v2 = tp[2];
        const float xq = v0.x, yq = v0.y, xr = v1.x, yr = v1.y, xs = v2.x, ys = v2.y;
        const float det  = xq * (yr - ys) + xr * (ys - yq) + xs * (yq - yr);
        const float area = fabsf(0.5f * det);
        const float a2   = 2.0f * area;
        sA[threadIdx.x] = make_float4(xq, yq, xr - xq, yr - yq);
        sB[threadIdx.x] = make_float4(xs - xr, ys - yr, a2, a2 * (1.0f / FOURPI2_F));
    }
    __syncthreads();

    // U = Wx[h], V = Wy[w] from the validated constant table.
    float U;
    if (h < 31)       U = -c_posw[30 - h];
    else if (h == 31) U = 0.0f;
    else if (h < 63)  U = c_posw[h - 32];
    else              U = 0.0f;   // padded row (masked before output)
    const float V = (w == 0) ? 0.0f : c_posw[w - 1];

    float accR = 0.0f, accI = 0.0f;

    // Quad loop: wave wv evaluates (n, n+4, n+8, n+12) together; per-wave
    // accumulation order (wv, wv+4, wv+8, ...) is preserved exactly.
    int n = wv;
    for (; n + 3 * NWAVE < N; n += 4 * NWAVE) {
        const Pre ea = pre_eval(U, V, sA[n],             sB[n]);
        const Pre eb = pre_eval(U, V, sA[n +     NWAVE], sB[n +     NWAVE]);
        const Pre ec = pre_eval(U, V, sA[n + 2 * NWAVE], sB[n + 2 * NWAVE]);
        const Pre ed = pre_eval(U, V, sA[n + 3 * NWAVE], sB[n + 3 * NWAVE]);

        if (__ballot(ea.sp || eb.sp || ec.sp || ed.sp)) {
            eval_slow(ea, accR, accI);
            eval_slow(eb, accR, accI);
            eval_slow(ec, accR, accI);
            eval_slow(ed, accR, accI);
        } else {
            eval_fast(ea, accR, accI);
            eval_fast(eb, accR, accI);
            eval_fast(ec, accR, accI);
            eval_fast(ed, accR, accI);
        }
    }

    // Pair remainder.
    for (; n + NWAVE < N; n += 2 * NWAVE) {
        const Pre ea = pre_eval(U, V, sA[n],         sB[n]);
        const Pre eb = pre_eval(U, V, sA[n + NWAVE], sB[n + NWAVE]);
        if (__ballot(ea.sp || eb.sp)) {
            eval_slow(ea, accR, accI);
            eval_slow(eb, accR, accI);
        } else {
            eval_fast(ea, accR, accI);
            eval_fast(eb, accR, accI);
        }
    }

    // Single remainder (at most one triangle per wave).
    for (; n < N; n += NWAVE) {
        const Pre ea = pre_eval(U, V, sA[n], sB[n]);
        if (__ballot(ea.sp)) {
            eval_slow(ea, accR, accI);
        } else {
            eval_fast(ea, accR, accI);
        }
    }

    s_red[wv][lane] = make_float2(accR, accI);
    __syncthreads();

    if (wv == 0) {
        float R = 0.0f, I = 0.0f;
#pragma unroll
        for (int k = 0; k < NWAVE; ++k) {
            const float2 v = s_red[k][lane];
            R += v.x;
            I += v.y;
        }
        // numpy's masked segment-sum adds exact +0.0 for invalid slots,
        // flipping -0.0 -> +0.0; reproduce (affects only zero signs).
        R += 0.0f;
        I += 0.0f;

        if (h == 63) { R = 0.0f; I = 0.0f; }   // pad row

        const float m2 = __fadd_rn(__fmul_rn(R, R), __fmul_rn(I, I));
        float mag, ph;
        if (m2 == 0.0f) {
            mag = 0.0f;
            ph  = atan2f(I, 1.0f);   // angle(0) = 0 semantics
        } else {
            mag = log1pf(sqrtf(m2));
            ph  = atan2f(I, R);
        }

        const int o = b * NFREQ + p;
        out[o]              = mag;   // mag block [64,1,64,32]
        out[BB * NFREQ + o] = ph;    // phase block follows
    }
}

extern "C" void kernel_launch(void* const* d_in, const int* in_sizes, int n_in,
                              void* d_out, int out_size, void* d_ws, size_t ws_size,
                              hipStream_t stream) {
    const float* tris    = (const float*)d_in[0]; // [64,128,3,2] f32
    const int*   lengths = (const int*)d_in[1];   // [64] i32
    float*       out     = (float*)d_out;         // [2*64*2048] f32

    poly_cft_fused<<<dim3(PGRPS, BB), dim3(BLK), 0, stream>>>(tris, lengths, out);
}